// Round 3
// baseline (558.186 us; speedup 1.0000x reference)
//
#include <hip/hip_runtime.h>
#include <cstdint>
#include <cstddef>

// Sizes (fixed by the reference)
#define B_    32
#define CIN_  32
#define COUT_ 32
#define HH    128
#define WW    128
#define CDIM  256
#define NP    9216     // CIN*COUT*3*3
#define HID   4608
#define KSPLIT 4
#define KPER  (HID/KSPLIT)   // 1152

// ---------------- Kernel 1: h[b][j] = relu(cond[b] . W1[j] + b1[j]) ----------------
__global__ __launch_bounds__(256)
void mlp1_k(const float* __restrict__ cond, const float* __restrict__ W1,
            const float* __restrict__ b1, float* __restrict__ h) {
    __shared__ float cs[CDIM];
    const int b  = blockIdx.x / (HID/256);
    const int jb = blockIdx.x % (HID/256);
    const int tid = threadIdx.x;
    cs[tid] = cond[b*CDIM + tid];
    __syncthreads();
    const int j = jb*256 + tid;
    const float4* wr = reinterpret_cast<const float4*>(W1 + (size_t)j*CDIM);
    float acc = b1[j];
    #pragma unroll 4
    for (int c = 0; c < CDIM/4; ++c) {
        float4 w = wr[c];
        acc += w.x*cs[4*c] + w.y*cs[4*c+1] + w.z*cs[4*c+2] + w.w*cs[4*c+3];
    }
    h[b*HID + j] = fmaxf(acc, 0.f);
}

// ---------------- Kernel 2: partial[ks][b][p] = sum_{k in split ks} h[b][k]*W2[p][k] ----
// Block: 64 p-rows x all 32 batches x one K-split (1152). 256 threads = 4 waves.
// Wave w handles batches 8w..8w+7; lane = p_local. W2 read once, coalesced, staged in LDS.
__global__ __launch_bounds__(256)
void mlp2_k(const float* __restrict__ h, const float* __restrict__ W2,
            float* __restrict__ part) {
    __shared__ float hs[B_*68];    // [b][64+pad4]
    __shared__ float w2s[64*68];   // [p][64+pad4]
    const int pblk = blockIdx.x >> 2;
    const int ks   = blockIdx.x & 3;
    const int p0   = pblk * 64;
    const int tid  = threadIdx.x;
    const int pl   = tid & 63;     // lane = p_local
    const int bg   = tid >> 6;     // wave id -> batch group
    float acc[8] = {0,0,0,0,0,0,0,0};
    const int kbase0 = ks * KPER;
    for (int kt = 0; kt < KPER/64; ++kt) {
        const int kb = kbase0 + kt*64;
        __syncthreads();           // protect LDS reuse from previous tile
        for (int i = tid; i < B_*64; i += 256) {        // stage h tile (coalesced)
            int bb = i >> 6, kk = i & 63;
            hs[bb*68 + kk] = h[bb*HID + kb + kk];
        }
        for (int q = tid; q < 64*16; q += 256) {        // stage W2 tile (float4, coalesced)
            int pp = q >> 4, kq = (q & 15) << 2;
            float4 v = *reinterpret_cast<const float4*>(W2 + (size_t)(p0+pp)*HID + kb + kq);
            *reinterpret_cast<float4*>(&w2s[pp*68 + kq]) = v;
        }
        __syncthreads();
        #pragma unroll 4
        for (int k4 = 0; k4 < 16; ++k4) {
            float4 wv = *reinterpret_cast<const float4*>(&w2s[pl*68 + k4*4]);
            #pragma unroll
            for (int i = 0; i < 8; ++i) {   // hs read: wave-uniform addr -> broadcast
                float4 hv = *reinterpret_cast<const float4*>(&hs[(bg*8+i)*68 + k4*4]);
                acc[i] += wv.x*hv.x + wv.y*hv.y + wv.z*hv.z + wv.w*hv.w;
            }
        }
    }
    float* dst = part + (size_t)ks*B_*NP;
    #pragma unroll
    for (int i = 0; i < 8; ++i)
        dst[(size_t)(bg*8+i)*NP + p0 + pl] = acc[i];   // coalesced over lanes
}

// ---------------- Kernel 3: wt[b][ci][k9][co] = sum_ks part[ks][b][p] + b2[p] ---------
// Combines the K-split partials AND permutes to conv-friendly layout:
//   original p = co*288 + ci*9 + k9   ->   dest r*32 + co  (r = ci*9+k9)
// so conv_k's weight staging becomes a straight coalesced copy.
__global__ __launch_bounds__(256)
void reduce_k(const float* __restrict__ part, const float* __restrict__ b2,
              float* __restrict__ wt) {
    const int idx = blockIdx.x*256 + threadIdx.x;          // quad index < 73728
    const float4* p4 = reinterpret_cast<const float4*>(part);
    const size_t stride = (size_t)B_*NP/4;
    float4 a = p4[idx];
    float4 b = p4[idx + stride];
    float4 c = p4[idx + 2*stride];
    float4 d = p4[idx + 3*stride];
    const int pq = idx % (NP/4);
    const int bi = idx / (NP/4);
    float4 bb = reinterpret_cast<const float4*>(b2)[pq];
    float o0 = a.x+b.x+c.x+d.x+bb.x;
    float o1 = a.y+b.y+c.y+d.y+bb.y;
    float o2 = a.z+b.z+c.z+d.z+bb.z;
    float o3 = a.w+b.w+c.w+d.w+bb.w;
    const int p  = pq << 2;
    const int co = p / 288;            // 288 = CIN_*9; quad never crosses co boundary
    const int r  = p - co*288;         // r..r+3 = ci*9+k9 consecutive
    float* dst = wt + (size_t)bi*NP + r*32 + co;
    dst[0]  = o0;                      // scattered stride-128B stores; L2-absorbed (1.2MB)
    dst[32] = o1;
    dst[64] = o2;
    dst[96] = o3;
}

// ---------------- Kernel 4: per-sample 3x3 conv (pad 1, stride 1) ----------------
// Block = (b, 4 output rows). 256 threads: rp = tid>>7 (row-pair), cg = (tid>>4)&7
// (cout-quad), colb = tid&15 (8-col block). 4 cin-groups of 8; per group stage
// xs[8][6][132] (zero-padded, 25.3 KB) and wt slice [8][9][32] (9 KB, coalesced copy
// thanks to reduce_k's permuted layout). Per thread: acc[2 rows][4 couts][8 cols].
// Weight float4 loaded inside the (t,kh) loop to keep live VGPRs ~100 so
// __launch_bounds__(256,4) holds 4 blocks/CU (grid 1024 = exactly 4/CU, no tail).
// Per ci per wave: VALU 576 FMA x 2cyc = 1152 cyc vs LDS 30 b128 x 12cyc = 360 cyc
// -> VALU-bound.
#define CG 8
__global__ __launch_bounds__(256, 4)
void conv_k(const float* __restrict__ x, const float* __restrict__ wt,
            float* __restrict__ out) {
    __shared__ float xs[CG*6*132];     // 6336 floats
    __shared__ float wsh[CG*9*32];     // 2304 floats, layout [ci][k9][co]
    const int b   = blockIdx.x >> 5;
    const int r0  = (blockIdx.x & 31) << 2;       // 4 output rows r0..r0+3
    const int tid = threadIdx.x;
    const int colb = tid & 15;
    const int cg   = (tid >> 4) & 7;
    const int rp   = tid >> 7;
    const int col8 = colb << 3;
    float acc[2][4][8] = {};
    for (int g = 0; g < 4; ++g) {
        const int c0 = g * CG;
        __syncthreads();   // previous group's compute must finish before restage
        // stage x tile: rows r0-1 .. r0+4, cols -1..130, zero-padded
        for (int i = tid; i < CG*6*132; i += 256) {
            int ci  = i / 792;
            int rem = i - ci*792;
            int rr  = rem / 132;
            int cp  = rem - rr*132;
            int gr  = r0 - 1 + rr;
            int gc  = cp - 1;
            float v = 0.f;
            if ((unsigned)gr < HH && (unsigned)gc < WW)
                v = x[(((size_t)b*CIN_ + c0 + ci)*HH + gr)*WW + gc];
            xs[i] = v;
        }
        // stage weights: coalesced float4 copy (wt already [ci][k9][co])
        {
            const float4* src4 = reinterpret_cast<const float4*>(
                wt + (size_t)b*NP + c0*9*32);
            float4* dst4 = reinterpret_cast<float4*>(wsh);
            for (int q = tid; q < CG*9*32/4; q += 256)
                dst4[q] = src4[q];
        }
        __syncthreads();
        for (int ci = 0; ci < CG; ++ci) {
            #pragma unroll
            for (int t = 0; t < 4; ++t) {         // input rows (thread window)
                float xrow[12];
                {
                    const float4* p4 = reinterpret_cast<const float4*>(
                        &xs[(ci*6 + 2*rp + t)*132 + col8]);
                    float4 q0 = p4[0], q1 = p4[1], q2 = p4[2];
                    xrow[0]=q0.x; xrow[1]=q0.y; xrow[2] =q0.z; xrow[3] =q0.w;
                    xrow[4]=q1.x; xrow[5]=q1.y; xrow[6] =q1.z; xrow[7] =q1.w;
                    xrow[8]=q2.x; xrow[9]=q2.y; xrow[10]=q2.z; xrow[11]=q2.w;
                }
                #pragma unroll
                for (int kh = 0; kh < 3; ++kh) {
                    const int ro = t - kh;        // output row this (t,kh) feeds
                    if (ro < 0 || ro > 1) continue;
                    #pragma unroll
                    for (int kw = 0; kw < 3; ++kw) {
                        const float4 w4 = *reinterpret_cast<const float4*>(
                            &wsh[(ci*9 + kh*3 + kw)*32 + cg*4]);
                        #pragma unroll
                        for (int cl = 0; cl < 8; ++cl) {
                            const float xv = xrow[cl + kw];
                            acc[ro][0][cl] = fmaf(xv, w4.x, acc[ro][0][cl]);
                            acc[ro][1][cl] = fmaf(xv, w4.y, acc[ro][1][cl]);
                            acc[ro][2][cl] = fmaf(xv, w4.z, acc[ro][2][cl]);
                            acc[ro][3][cl] = fmaf(xv, w4.w, acc[ro][3][cl]);
                        }
                    }
                }
            }
        }
    }
    #pragma unroll
    for (int ro = 0; ro < 2; ++ro) {
        const int row = r0 + 2*rp + ro;
        #pragma unroll
        for (int c = 0; c < 4; ++c) {
            const int cout = cg*4 + c;
            float* dst = out + (((size_t)b*COUT_ + cout)*HH + row)*WW + col8;
            *reinterpret_cast<float4*>(dst) =
                make_float4(acc[ro][c][0], acc[ro][c][1], acc[ro][c][2], acc[ro][c][3]);
            *reinterpret_cast<float4*>(dst + 4) =
                make_float4(acc[ro][c][4], acc[ro][c][5], acc[ro][c][6], acc[ro][c][7]);
        }
    }
}

extern "C" void kernel_launch(void* const* d_in, const int* in_sizes, int n_in,
                              void* d_out, int out_size, void* d_ws, size_t ws_size,
                              hipStream_t stream) {
    const float* x    = (const float*)d_in[0];
    const float* cond = (const float*)d_in[1];
    const float* W1   = (const float*)d_in[2];
    const float* b1   = (const float*)d_in[3];
    const float* W2   = (const float*)d_in[4];
    const float* b2   = (const float*)d_in[5];
    float* out = (float*)d_out;

    // Workspace layout (~6.2 MiB):
    //   h:    B*HID        floats @ 0         (589824 B)
    //   part: KSPLIT*B*NP  floats @ 589824    (4718592 B)
    //   wt:   B*NP         floats @ 5308416   (1179648 B)  [b][ci*9+k9][co] layout
    char* ws = (char*)d_ws;
    float* h    = (float*)(ws);
    float* part = (float*)(ws + 589824);
    float* wt   = (float*)(ws + 589824 + 4718592);

    hipLaunchKernelGGL(mlp1_k,   dim3(B_*(HID/256)),    dim3(256), 0, stream, cond, W1, b1, h);
    hipLaunchKernelGGL(mlp2_k,   dim3((NP/64)*KSPLIT),  dim3(256), 0, stream, h, W2, part);
    hipLaunchKernelGGL(reduce_k, dim3((B_*NP/4)/256),   dim3(256), 0, stream, part, b2, wt);
    hipLaunchKernelGGL(conv_k,   dim3(B_*(HH/4)),       dim3(256), 0, stream, x, wt, out);
}